// Round 1
// baseline (6358.347 us; speedup 1.0000x reference)
//
#include <hip/hip_runtime.h>
#include <math.h>

#define B 64
#define TIN 128
#define N_IN 256
#define M 1024
#define O_DIM 512
#define LM 2048
#define TDEC 64
#define M3 3072
#define CH 8   // encoder gi timestep chunk

typedef short bf16x8 __attribute__((ext_vector_type(8)));
typedef float floatx4 __attribute__((ext_vector_type(4)));

__device__ __forceinline__ unsigned short f2bf(float f) {
    unsigned int u = __float_as_uint(f);
    u += 0x7FFFu + ((u >> 16) & 1u);      // round-to-nearest-even
    return (unsigned short)(u >> 16);
}
__device__ __forceinline__ float sigm(float x) { return 1.f / (1.f + expf(-x)); }

// ---------------------------------------------------------------------------
// fp32 -> bf16 cast (weights, Y0)
// ---------------------------------------------------------------------------
__global__ __launch_bounds__(256) void cast_bf(const float* __restrict__ in,
                                               short* __restrict__ out, int n) {
    int i = blockIdx.x * 256 + threadIdx.x;
    if (i < n) out[i] = (short)f2bf(in[i]);
}

// ---------------------------------------------------------------------------
// X (B,TIN,N) fp32 -> Xt (TIN,B,N) bf16
// ---------------------------------------------------------------------------
__global__ __launch_bounds__(256) void transpose_X_bf(const float* __restrict__ X,
                                                      short* __restrict__ Xt) {
    int idx = blockIdx.x * 256 + threadIdx.x;   // t*(B*N) + b*N + n
    int n = idx & (N_IN - 1);
    int b = (idx >> 8) & (B - 1);
    int t = idx >> 14;
    Xt[idx] = (short)f2bf(X[(b * TIN + t) * N_IN + n]);
}

// ---------------------------------------------------------------------------
// Batched MFMA GEMM (encoder layer-0 gi chunks):
// C[r][c] = sum_k A[r][k]*W[c][k] + bias[c]; one 16x16 tile per wave.
// grid=(cols/16, rows/64), block=256.
// ---------------------------------------------------------------------------
__global__ __launch_bounds__(256) void mfma_gemm_bias(
    const short* __restrict__ A, int lda,
    const short* __restrict__ W, int ldw,
    const float* __restrict__ bias,
    float* __restrict__ C, int ldc, int K) {
    int wave = threadIdx.x >> 6;
    int lane = threadIdx.x & 63;
    int r0 = blockIdx.y * 64 + wave * 16;
    int c0 = blockIdx.x * 16;
    int lrow = lane & 15;
    int ko8 = (lane >> 4) * 8;
    const short* ap = A + (size_t)(r0 + lrow) * lda + ko8;
    const short* wp = W + (size_t)(c0 + lrow) * ldw + ko8;
    floatx4 acc = {0.f, 0.f, 0.f, 0.f};
    #pragma unroll 4
    for (int k = 0; k < K; k += 32) {
        bf16x8 a = *(const bf16x8*)(ap + k);
        bf16x8 b = *(const bf16x8*)(wp + k);
        acc = __builtin_amdgcn_mfma_f32_16x16x32_bf16(a, b, acc, 0, 0, 0);
    }
    int col = c0 + lrow;
    float bv = bias[col];
    int rbase = r0 + (lane >> 4) * 4;
    #pragma unroll
    for (int i = 0; i < 4; i++)
        C[(size_t)(rbase + i) * ldc + col] = acc[i] + bv;
}

// ---------------------------------------------------------------------------
// GRU step core (dec-style: gi = x@Wih.T fused with gh = h@Whh.T), K-split
// across 4 waves, LDS reduce. Used by decoder gru1 and encoder layer-1 role.
// ---------------------------------------------------------------------------
__device__ __forceinline__ void gru_dec_core(
    const short* x_bf, int Kx,
    const short* Wih,
    const short* h_in_bf, const short* Whh,
    const float* bih, const float* bhh,
    float* h_f, short* h_out_bf,
    float (*lr)[64][4], float (*lz)[64][4],
    float (*li)[64][4], float (*lh)[64][4]) {
    int wave = threadIdx.x >> 6;
    int lane = threadIdx.x & 63;
    int m0 = blockIdx.x * 16;
    int r0 = blockIdx.y * 16;
    int lrow = lane & 15;
    int ko8 = (lane >> 4) * 8;
    floatx4 ar = {0.f, 0.f, 0.f, 0.f};
    floatx4 az = {0.f, 0.f, 0.f, 0.f};
    floatx4 ain = {0.f, 0.f, 0.f, 0.f};
    floatx4 ahn = {0.f, 0.f, 0.f, 0.f};
    {   // input-side quarter
        int Kq = Kx >> 2;
        const short* ap = x_bf + (size_t)(r0 + lrow) * Kx + wave * Kq + ko8;
        const short* wr = Wih + (size_t)(m0 + lrow) * Kx + wave * Kq + ko8;
        const short* wz = wr + (size_t)M * Kx;
        const short* wn = wr + (size_t)2 * M * Kx;
        #pragma unroll
        for (int k = 0; k < Kq; k += 32) {
            bf16x8 a = *(const bf16x8*)(ap + k);
            ar  = __builtin_amdgcn_mfma_f32_16x16x32_bf16(a, *(const bf16x8*)(wr + k), ar, 0, 0, 0);
            az  = __builtin_amdgcn_mfma_f32_16x16x32_bf16(a, *(const bf16x8*)(wz + k), az, 0, 0, 0);
            ain = __builtin_amdgcn_mfma_f32_16x16x32_bf16(a, *(const bf16x8*)(wn + k), ain, 0, 0, 0);
        }
    }
    {   // hidden-side quarter
        const int Kq = M >> 2;
        const short* ap = h_in_bf + (size_t)(r0 + lrow) * M + wave * Kq + ko8;
        const short* wr = Whh + (size_t)(m0 + lrow) * M + wave * Kq + ko8;
        const short* wz = wr + (size_t)M * M;
        const short* wn = wr + (size_t)2 * M * M;
        #pragma unroll
        for (int k = 0; k < Kq; k += 32) {
            bf16x8 a = *(const bf16x8*)(ap + k);
            ar  = __builtin_amdgcn_mfma_f32_16x16x32_bf16(a, *(const bf16x8*)(wr + k), ar, 0, 0, 0);
            az  = __builtin_amdgcn_mfma_f32_16x16x32_bf16(a, *(const bf16x8*)(wz + k), az, 0, 0, 0);
            ahn = __builtin_amdgcn_mfma_f32_16x16x32_bf16(a, *(const bf16x8*)(wn + k), ahn, 0, 0, 0);
        }
    }
    #pragma unroll
    for (int i = 0; i < 4; i++) {
        lr[wave][lane][i] = ar[i];
        lz[wave][lane][i] = az[i];
        li[wave][lane][i] = ain[i];
        lh[wave][lane][i] = ahn[i];
    }
    __syncthreads();
    int row = threadIdx.x >> 4, col = threadIdx.x & 15;
    int sl = (row >> 2) * 16 + col, rg = row & 3;
    float sr = lr[0][sl][rg] + lr[1][sl][rg] + lr[2][sl][rg] + lr[3][sl][rg];
    float sz = lz[0][sl][rg] + lz[1][sl][rg] + lz[2][sl][rg] + lz[3][sl][rg];
    float si = li[0][sl][rg] + li[1][sl][rg] + li[2][sl][rg] + li[3][sl][rg];
    float sh = lh[0][sl][rg] + lh[1][sl][rg] + lh[2][sl][rg] + lh[3][sl][rg];
    int b = r0 + row, m = m0 + col;
    float r = sigm(sr + bih[m] + bhh[m]);
    float z = sigm(sz + bih[M + m] + bhh[M + m]);
    float n = tanhf(si + bih[2 * M + m] + r * (sh + bhh[2 * M + m]));
    size_t hi = (size_t)b * M + m;
    float hv = (1.f - z) * n + z * h_f[hi];
    h_f[hi] = hv;
    h_out_bf[hi] = (short)f2bf(hv);
}

// ---------------------------------------------------------------------------
// Decoder GRU layer-1 step (standalone).
// grid=(M/16, B/16), block=256. Kx % 128 == 0.
// ---------------------------------------------------------------------------
__global__ __launch_bounds__(256) void gru_step_dec(
    const short* __restrict__ x_bf, int Kx,
    const short* __restrict__ Wih,
    const short* __restrict__ h_in_bf, const short* __restrict__ Whh,
    const float* __restrict__ bih, const float* __restrict__ bhh,
    float* __restrict__ h_f, short* __restrict__ h_out_bf) {
    __shared__ float lds[4][4][64][4];
    gru_dec_core(x_bf, Kx, Wih, h_in_bf, Whh, bih, bhh, h_f, h_out_bf,
                 lds[0], lds[1], lds[2], lds[3]);
}

// ---------------------------------------------------------------------------
// Fused encoder step: blockIdx.z==0 -> layer0 gru step t (gi precomputed),
// blockIdx.z==1 -> layer1 gru step t-1 (dec-style, gi folded in, x=seqA[t-1]).
// grid=(M/16, B/16, 2), block=256.
// ---------------------------------------------------------------------------
__global__ __launch_bounds__(256) void enc_step(
    const short* __restrict__ h0_in, const short* __restrict__ Whh0,
    const float* __restrict__ gi, const float* __restrict__ bhh0,
    float* __restrict__ h0f, short* __restrict__ h0_out, short* __restrict__ seq_out,
    const short* __restrict__ x1, const short* __restrict__ Wih1,
    const short* __restrict__ h1_in, const short* __restrict__ Whh1,
    const float* __restrict__ bih1, const float* __restrict__ bhh1,
    float* __restrict__ h1f, short* __restrict__ h1_out) {
    __shared__ float lds[4][4][64][4];
    if (blockIdx.z == 1) {
        if (!x1) return;   // t == 0: layer1 not started yet
        gru_dec_core(x1, M, Wih1, h1_in, Whh1, bih1, bhh1, h1f, h1_out,
                     lds[0], lds[1], lds[2], lds[3]);
        return;
    }
    if (!gi) return;       // t == TIN: layer0 finished
    int wave = threadIdx.x >> 6;
    int lane = threadIdx.x & 63;
    int m0 = blockIdx.x * 16;
    int r0 = blockIdx.y * 16;
    int lrow = lane & 15;
    int ko8 = (lane >> 4) * 8;
    const int Kq = M >> 2;                       // 256
    const short* ap = h0_in + (size_t)(r0 + lrow) * M + wave * Kq + ko8;
    const short* wr = Whh0 + (size_t)(m0 + lrow) * M + wave * Kq + ko8;
    const short* wz = wr + (size_t)M * M;
    const short* wn = wr + (size_t)2 * M * M;
    floatx4 ar = {0.f, 0.f, 0.f, 0.f};
    floatx4 az = {0.f, 0.f, 0.f, 0.f};
    floatx4 ahn = {0.f, 0.f, 0.f, 0.f};
    #pragma unroll
    for (int k = 0; k < Kq; k += 32) {
        bf16x8 a = *(const bf16x8*)(ap + k);
        ar  = __builtin_amdgcn_mfma_f32_16x16x32_bf16(a, *(const bf16x8*)(wr + k), ar, 0, 0, 0);
        az  = __builtin_amdgcn_mfma_f32_16x16x32_bf16(a, *(const bf16x8*)(wz + k), az, 0, 0, 0);
        ahn = __builtin_amdgcn_mfma_f32_16x16x32_bf16(a, *(const bf16x8*)(wn + k), ahn, 0, 0, 0);
    }
    #pragma unroll
    for (int i = 0; i < 4; i++) {
        lds[0][wave][lane][i] = ar[i];
        lds[1][wave][lane][i] = az[i];
        lds[2][wave][lane][i] = ahn[i];
    }
    __syncthreads();
    int row = threadIdx.x >> 4, col = threadIdx.x & 15;
    int sl = (row >> 2) * 16 + col, rg = row & 3;
    float sr = lds[0][0][sl][rg] + lds[0][1][sl][rg] + lds[0][2][sl][rg] + lds[0][3][sl][rg];
    float sz = lds[1][0][sl][rg] + lds[1][1][sl][rg] + lds[1][2][sl][rg] + lds[1][3][sl][rg];
    float sn = lds[2][0][sl][rg] + lds[2][1][sl][rg] + lds[2][2][sl][rg] + lds[2][3][sl][rg];
    int b = r0 + row, m = m0 + col;
    const float* gir = gi + (size_t)b * M3;
    float r = sigm(gir[m] + sr + bhh0[m]);
    float z = sigm(gir[M + m] + sz + bhh0[M + m]);
    float n = tanhf(gir[2 * M + m] + r * (sn + bhh0[2 * M + m]));
    size_t hi = (size_t)b * M + m;
    float hv = (1.f - z) * n + z * h0f[hi];
    h0f[hi] = hv;
    short hb = (short)f2bf(hv);
    h0_out[hi] = hb;
    seq_out[hi] = hb;
}

// ---------------------------------------------------------------------------
// Decoder GRU layer-0 step with fused softmax of previous logits.
// Each block softmaxes its own 16 batch rows into LDS (XOR-swizzled) and uses
// that as the MFMA A-operand for the input-side GEMM (Kx = O_DIM = 512).
// prev_logits==null -> first step, read Y0 (bf16) instead.
// grid=(M/16, B/16), block=256.
// ---------------------------------------------------------------------------
__global__ __launch_bounds__(256) void gru0_sm(
    const float* __restrict__ prev_logits, int ldl,
    const short* __restrict__ y0_bf,
    const short* __restrict__ Wih,
    const short* __restrict__ h_in_bf, const short* __restrict__ Whh,
    const float* __restrict__ bih, const float* __restrict__ bhh,
    float* __restrict__ h_f, short* __restrict__ h_out_bf) {
    __shared__ short xs[16 * O_DIM];             // 16 KB, XOR-swizzled
    __shared__ float lds[4][4][64][4];           // 16 KB reduce buffers
    int wave = threadIdx.x >> 6;
    int lane = threadIdx.x & 63;
    int m0 = blockIdx.x * 16;
    int r0 = blockIdx.y * 16;
    // ---- stage A rows (softmax or bf16 copy) into xs ----
    int rr = wave * 4 + (lane >> 4);             // row 0..15 of this block
    int cl = lane & 15;                          // 16 lanes cooperate per row
    if (prev_logits) {
        const float* rowp = prev_logits + (size_t)(r0 + rr) * ldl + cl * 32;
        float v[32];
        float mx = -3.4e38f;
        #pragma unroll
        for (int j = 0; j < 32; j++) { v[j] = rowp[j]; mx = fmaxf(mx, v[j]); }
        #pragma unroll
        for (int off = 1; off < 16; off <<= 1) mx = fmaxf(mx, __shfl_xor(mx, off, 16));
        float s = 0.f;
        #pragma unroll
        for (int j = 0; j < 32; j++) { v[j] = __expf(v[j] - mx); s += v[j]; }
        #pragma unroll
        for (int off = 1; off < 16; off <<= 1) s += __shfl_xor(s, off, 16);
        float inv = 1.f / s;
        #pragma unroll
        for (int j = 0; j < 32; j += 2) {
            unsigned int pk = (unsigned int)f2bf(v[j] * inv)
                            | ((unsigned int)f2bf(v[j + 1] * inv) << 16);
            int byte = ((rr * O_DIM + cl * 32 + j) * 2) ^ ((rr & 7) << 4);
            *(unsigned int*)((char*)xs + byte) = pk;
        }
    } else {
        const short* rowp = y0_bf + (size_t)(r0 + rr) * O_DIM + cl * 32;
        #pragma unroll
        for (int j = 0; j < 32; j += 2) {
            unsigned int pk = (unsigned int)(unsigned short)rowp[j]
                            | ((unsigned int)(unsigned short)rowp[j + 1] << 16);
            int byte = ((rr * O_DIM + cl * 32 + j) * 2) ^ ((rr & 7) << 4);
            *(unsigned int*)((char*)xs + byte) = pk;
        }
    }
    __syncthreads();
    // ---- GEMM: input side from LDS, hidden side from global ----
    int lrow = lane & 15;
    int ko8 = (lane >> 4) * 8;
    floatx4 ar = {0.f, 0.f, 0.f, 0.f};
    floatx4 az = {0.f, 0.f, 0.f, 0.f};
    floatx4 ain = {0.f, 0.f, 0.f, 0.f};
    floatx4 ahn = {0.f, 0.f, 0.f, 0.f};
    {   // input-side quarter (Kx = 512)
        const int Kq = O_DIM >> 2;               // 128
        const short* wr = Wih + (size_t)(m0 + lrow) * O_DIM + wave * Kq + ko8;
        const short* wz = wr + (size_t)M * O_DIM;
        const short* wn = wr + (size_t)2 * M * O_DIM;
        #pragma unroll
        for (int k = 0; k < Kq; k += 32) {
            int abyte = ((lrow * O_DIM + wave * Kq + ko8 + k) * 2) ^ ((lrow & 7) << 4);
            bf16x8 a = *(const bf16x8*)((const char*)xs + abyte);
            ar  = __builtin_amdgcn_mfma_f32_16x16x32_bf16(a, *(const bf16x8*)(wr + k), ar, 0, 0, 0);
            az  = __builtin_amdgcn_mfma_f32_16x16x32_bf16(a, *(const bf16x8*)(wz + k), az, 0, 0, 0);
            ain = __builtin_amdgcn_mfma_f32_16x16x32_bf16(a, *(const bf16x8*)(wn + k), ain, 0, 0, 0);
        }
    }
    {   // hidden-side quarter
        const int Kq = M >> 2;
        const short* ap = h_in_bf + (size_t)(r0 + lrow) * M + wave * Kq + ko8;
        const short* wr = Whh + (size_t)(m0 + lrow) * M + wave * Kq + ko8;
        const short* wz = wr + (size_t)M * M;
        const short* wn = wr + (size_t)2 * M * M;
        #pragma unroll
        for (int k = 0; k < Kq; k += 32) {
            bf16x8 a = *(const bf16x8*)(ap + k);
            ar  = __builtin_amdgcn_mfma_f32_16x16x32_bf16(a, *(const bf16x8*)(wr + k), ar, 0, 0, 0);
            az  = __builtin_amdgcn_mfma_f32_16x16x32_bf16(a, *(const bf16x8*)(wz + k), az, 0, 0, 0);
            ahn = __builtin_amdgcn_mfma_f32_16x16x32_bf16(a, *(const bf16x8*)(wn + k), ahn, 0, 0, 0);
        }
    }
    #pragma unroll
    for (int i = 0; i < 4; i++) {
        lds[0][wave][lane][i] = ar[i];
        lds[1][wave][lane][i] = az[i];
        lds[2][wave][lane][i] = ain[i];
        lds[3][wave][lane][i] = ahn[i];
    }
    __syncthreads();
    int row = threadIdx.x >> 4, col = threadIdx.x & 15;
    int sl = (row >> 2) * 16 + col, rg = row & 3;
    float sr = lds[0][0][sl][rg] + lds[0][1][sl][rg] + lds[0][2][sl][rg] + lds[0][3][sl][rg];
    float sz = lds[1][0][sl][rg] + lds[1][1][sl][rg] + lds[1][2][sl][rg] + lds[1][3][sl][rg];
    float si = lds[2][0][sl][rg] + lds[2][1][sl][rg] + lds[2][2][sl][rg] + lds[2][3][sl][rg];
    float sh = lds[3][0][sl][rg] + lds[3][1][sl][rg] + lds[3][2][sl][rg] + lds[3][3][sl][rg];
    int b = r0 + row, m = m0 + col;
    float r = sigm(sr + bih[m] + bhh[m]);
    float z = sigm(sz + bih[M + m] + bhh[M + m]);
    float n = tanhf(si + bih[2 * M + m] + r * (sh + bhh[2 * M + m]));
    size_t hi = (size_t)b * M + m;
    float hv = (1.f - z) * n + z * h_f[hi];
    h_f[hi] = hv;
    h_out_bf[hi] = (short)f2bf(hv);
}

// ---------------------------------------------------------------------------
// fc1 (K-split 16x16 GEMM) + per-row sum / sumsq accumulation for LayerNorm.
// stats layout: [0..B-1]=sum, [B..2B-1]=sumsq (pre-zeroed per step).
// grid=(LM/16, B/16), block=256.
// ---------------------------------------------------------------------------
__global__ __launch_bounds__(256) void fc1_stats(
    const short* __restrict__ A, int lda,
    const short* __restrict__ W, int ldw,
    const float* __restrict__ bias,
    float* __restrict__ C, int ldc, int K,
    float* __restrict__ stats) {
    __shared__ float lds[4][64][4];
    int wave = threadIdx.x >> 6;
    int lane = threadIdx.x & 63;
    int r0 = blockIdx.y * 16;
    int c0 = blockIdx.x * 16;
    int Kq = K >> 2;
    int lrow = lane & 15;
    int ko8 = (lane >> 4) * 8;
    const short* ap = A + (size_t)(r0 + lrow) * lda + wave * Kq + ko8;
    const short* wp = W + (size_t)(c0 + lrow) * ldw + wave * Kq + ko8;
    floatx4 acc = {0.f, 0.f, 0.f, 0.f};
    #pragma unroll 4
    for (int k = 0; k < Kq; k += 32) {
        bf16x8 a = *(const bf16x8*)(ap + k);
        bf16x8 b = *(const bf16x8*)(wp + k);
        acc = __builtin_amdgcn_mfma_f32_16x16x32_bf16(a, b, acc, 0, 0, 0);
    }
    #pragma unroll
    for (int i = 0; i < 4; i++) lds[wave][lane][i] = acc[i];
    __syncthreads();
    int row = threadIdx.x >> 4, col = threadIdx.x & 15;
    int sl = (row >> 2) * 16 + col, rg = row & 3;
    float s = lds[0][sl][rg] + lds[1][sl][rg] + lds[2][sl][rg] + lds[3][sl][rg];
    float val = s + bias[c0 + col];
    C[(size_t)(r0 + row) * ldc + (c0 + col)] = val;
    float sv = val, sq = val * val;
    #pragma unroll
    for (int off = 1; off < 16; off <<= 1) {
        sv += __shfl_xor(sv, off, 16);
        sq += __shfl_xor(sq, off, 16);
    }
    if ((threadIdx.x & 15) == 0) {
        atomicAdd(&stats[r0 + row], sv);
        atomicAdd(&stats[B + r0 + row], sq);
    }
}

// ---------------------------------------------------------------------------
// fc2 with LayerNorm + exact GELU applied inline to the A-operand (fp32 z).
// Writes raw logits (the kernel output); softmax deferred to next gru0_sm.
// grid=(O_DIM/16, B/16), block=256.
// ---------------------------------------------------------------------------
__global__ __launch_bounds__(256) void fc2_lngelu(
    const float* __restrict__ zrow,          // B x LM fp32
    const short* __restrict__ W,             // O x LM bf16
    const float* __restrict__ bias,
    const float* __restrict__ stats,         // [sum(B), sumsq(B)]
    const float* __restrict__ g, const float* __restrict__ bt,
    float* __restrict__ C, int ldc) {
    __shared__ float lds[4][64][4];
    int wave = threadIdx.x >> 6;
    int lane = threadIdx.x & 63;
    int r0 = blockIdx.y * 16;
    int c0 = blockIdx.x * 16;
    const int Kq = LM >> 2;                  // 512
    int lrow = lane & 15;
    int ko8 = (lane >> 4) * 8;
    int r = r0 + lrow;
    float mu = stats[r] * (1.f / LM);
    float var = stats[B + r] * (1.f / LM) - mu * mu;
    float inv = rsqrtf(var + 1e-5f);
    const float* zp = zrow + (size_t)r * LM + wave * Kq + ko8;
    const float* gp = g + wave * Kq + ko8;
    const float* bp = bt + wave * Kq + ko8;
    const short* wp = W + (size_t)(c0 + lrow) * LM + wave * Kq + ko8;
    floatx4 acc = {0.f, 0.f, 0.f, 0.f};
    for (int k = 0; k < Kq; k += 32) {
        bf16x8 a;
        #pragma unroll
        for (int j = 0; j < 8; j++) {
            float zn = (zp[k + j] - mu) * inv * gp[k + j] + bp[k + j];
            float ge = 0.5f * zn * (1.f + erff(zn * 0.70710678118654752f));
            a[j] = (short)f2bf(ge);
        }
        bf16x8 b = *(const bf16x8*)(wp + k);
        acc = __builtin_amdgcn_mfma_f32_16x16x32_bf16(a, b, acc, 0, 0, 0);
    }
    #pragma unroll
    for (int i = 0; i < 4; i++) lds[wave][lane][i] = acc[i];
    __syncthreads();
    int row = threadIdx.x >> 4, col = threadIdx.x & 15;
    int sl = (row >> 2) * 16 + col, rg = row & 3;
    float s = lds[0][sl][rg] + lds[1][sl][rg] + lds[2][sl][rg] + lds[3][sl][rg];
    C[(size_t)(r0 + row) * ldc + (c0 + col)] = s + bias[c0 + col];
}

extern "C" void kernel_launch(void* const* d_in, const int* in_sizes, int n_in,
                              void* d_out, int out_size, void* d_ws, size_t ws_size,
                              hipStream_t stream) {
    const float* X        = (const float*)d_in[0];
    const float* Y0       = (const float*)d_in[1];
    const float* enc_Wih0 = (const float*)d_in[2];
    const float* enc_Whh0 = (const float*)d_in[3];
    const float* enc_bih0 = (const float*)d_in[4];
    const float* enc_bhh0 = (const float*)d_in[5];
    const float* enc_Wih1 = (const float*)d_in[6];
    const float* enc_Whh1 = (const float*)d_in[7];
    const float* enc_bih1 = (const float*)d_in[8];
    const float* enc_bhh1 = (const float*)d_in[9];
    const float* dec_Wih0 = (const float*)d_in[10];
    const float* dec_Whh0 = (const float*)d_in[11];
    const float* dec_bih0 = (const float*)d_in[12];
    const float* dec_bhh0 = (const float*)d_in[13];
    const float* dec_Wih1 = (const float*)d_in[14];
    const float* dec_Whh1 = (const float*)d_in[15];
    const float* dec_bih1 = (const float*)d_in[16];
    const float* dec_bhh1 = (const float*)d_in[17];
    const float* fc1_w    = (const float*)d_in[18];
    const float* fc1_b    = (const float*)d_in[19];
    const float* ln_g     = (const float*)d_in[20];
    const float* ln_b     = (const float*)d_in[21];
    const float* fc2_w    = (const float*)d_in[22];
    const float* fc2_b    = (const float*)d_in[23];
    float* out = (float*)d_out;

    // ---- workspace carve-up ----
    char* p = (char*)d_ws;
    auto carve = [&](size_t bytes) {
        void* r = p;
        p += (bytes + 255) & ~(size_t)255;
        return r;
    };
    short* Xt    = (short*)carve((size_t)TIN * B * N_IN * 2);
    short* seqA  = (short*)carve((size_t)TIN * B * M * 2);
    float* gi_ch = (float*)carve((size_t)CH * B * M3 * 4);
    short* we_ih0 = (short*)carve((size_t)M3 * N_IN * 2);
    short* we_hh0 = (short*)carve((size_t)M3 * M * 2);
    short* we_ih1 = (short*)carve((size_t)M3 * M * 2);
    short* we_hh1 = (short*)carve((size_t)M3 * M * 2);
    short* wd_ih0 = (short*)carve((size_t)M3 * O_DIM * 2);
    short* wd_hh0 = (short*)carve((size_t)M3 * M * 2);
    short* wd_ih1 = (short*)carve((size_t)M3 * M * 2);
    short* wd_hh1 = (short*)carve((size_t)M3 * M * 2);
    short* wfc1   = (short*)carve((size_t)LM * M * 2);
    short* wfc2   = (short*)carve((size_t)O_DIM * LM * 2);
    float* h0f = (float*)carve((size_t)B * M * 4);
    float* h1f = (float*)carve((size_t)B * M * 4);
    short* h0b = (short*)carve((size_t)2 * B * M * 2);   // ping-pong
    short* h1b = (short*)carve((size_t)2 * B * M * 2);
    short* yb  = (short*)carve((size_t)B * O_DIM * 2);
    float* zb  = (float*)carve((size_t)B * LM * 4);
    float* lnstats = (float*)carve((size_t)TDEC * 2 * B * 4);

    auto cast = [&](const float* src, short* dst, int n) {
        cast_bf<<<(n + 255) / 256, 256, 0, stream>>>(src, dst, n);
    };
    cast(enc_Wih0, we_ih0, M3 * N_IN);
    cast(enc_Whh0, we_hh0, M3 * M);
    cast(enc_Wih1, we_ih1, M3 * M);
    cast(enc_Whh1, we_hh1, M3 * M);
    cast(dec_Wih0, wd_ih0, M3 * O_DIM);
    cast(dec_Whh0, wd_hh0, M3 * M);
    cast(dec_Wih1, wd_ih1, M3 * M);
    cast(dec_Whh1, wd_hh1, M3 * M);
    cast(fc1_w, wfc1, LM * M);
    cast(fc2_w, wfc2, O_DIM * LM);
    cast(Y0, yb, B * O_DIM);
    transpose_X_bf<<<(TIN * B * N_IN) / 256, 256, 0, stream>>>(X, Xt);

    hipMemsetAsync(h0f, 0, (size_t)B * M * 4, stream);
    hipMemsetAsync(h1f, 0, (size_t)B * M * 4, stream);
    hipMemsetAsync(h0b, 0, (size_t)B * M * 2, stream);   // parity-0 buffer
    hipMemsetAsync(h1b, 0, (size_t)B * M * 2, stream);
    hipMemsetAsync(lnstats, 0, (size_t)TDEC * 2 * B * 4, stream);

    // -------------------- encoder (layer-pipelined) --------------------
    // launch t: layer0 step t (t<TIN) || layer1 step t-1 (t>=1)
    for (int t = 0; t <= TIN; t++) {
        if (t < TIN && (t % CH) == 0) {
            int c = t / CH;
            mfma_gemm_bias<<<dim3(M3 / 16, CH * B / 64), 256, 0, stream>>>(
                Xt + (size_t)c * CH * B * N_IN, N_IN, we_ih0, N_IN, enc_bih0,
                gi_ch, M3, N_IN);
        }
        const float* gi_t = (t < TIN) ? gi_ch + (size_t)(t % CH) * B * M3 : nullptr;
        const short* x1 = (t >= 1) ? seqA + (size_t)(t - 1) * B * M : nullptr;
        int p0 = t & 1;                  // layer0 step t parity
        int p1 = (t - 1) & 1;            // layer1 step t-1 parity
        enc_step<<<dim3(M / 16, B / 16, 2), 256, 0, stream>>>(
            h0b + (size_t)p0 * B * M, we_hh0, gi_t, enc_bhh0,
            h0f, h0b + (size_t)(p0 ^ 1) * B * M,
            seqA + (size_t)(t < TIN ? t : 0) * B * M,
            x1, we_ih1, h1b + (size_t)(p1 & 1) * B * M, we_hh1,
            enc_bih1, enc_bhh1, h1f, h1b + (size_t)((p1 & 1) ^ 1) * B * M);
    }
    // after 128 steps both layers' live bf16 state is at parity 0.

    // -------------------- decoder (4 fused phases per step) --------------------
    dim3 gruGrid(M / 16, B / 16);
    for (int t = 0; t < TDEC; t++) {
        int pin = t & 1, pout = pin ^ 1;
        const float* plog = t ? out + (size_t)(t - 1) * O_DIM : nullptr;
        gru0_sm<<<gruGrid, 256, 0, stream>>>(
            plog, TDEC * O_DIM, yb, wd_ih0,
            h0b + (size_t)pin * B * M, wd_hh0,
            dec_bih0, dec_bhh0, h0f, h0b + (size_t)pout * B * M);
        gru_step_dec<<<gruGrid, 256, 0, stream>>>(
            h0b + (size_t)pout * B * M, M, wd_ih1,
            h1b + (size_t)pin * B * M, wd_hh1,
            dec_bih1, dec_bhh1, h1f, h1b + (size_t)pout * B * M);
        fc1_stats<<<dim3(LM / 16, B / 16), 256, 0, stream>>>(
            h1b + (size_t)pout * B * M, M, wfc1, M, fc1_b, zb, LM, M,
            lnstats + (size_t)t * 2 * B);
        fc2_lngelu<<<dim3(O_DIM / 16, B / 16), 256, 0, stream>>>(
            zb, wfc2, fc2_b, lnstats + (size_t)t * 2 * B, ln_g, ln_b,
            out + (size_t)t * O_DIM, TDEC * O_DIM);
    }
}